// Round 5
// baseline (1756.527 us; speedup 1.0000x reference)
//
#include <hip/hip_runtime.h>
#include <hip/hip_bf16.h>
#include <math.h>

// Problem constants
#define T_TOK 4096   // B*S tokens
#define D_IN  1024
#define H_DIM 2048
#define O_DIM 1024
#define NE    8
#define ROWCAP 9216  // 8192 routed rows + per-expert pad to 128
#define NBLK  512    // grid: 2 blocks/CU guaranteed by launch_bounds(256,2) + 36KB LDS
#define GBLK  128    // blocks [0,GBLK) gate; [GBLK,NBLK) convert weights in phase 0

typedef __bf16 bf16x8 __attribute__((ext_vector_type(8)));
typedef __bf16 bf16x4 __attribute__((ext_vector_type(4)));
typedef float  f32x4  __attribute__((ext_vector_type(4)));

#define ELT(f, j) ((j) == 0 ? (f).x : (j) == 1 ? (f).y : (j) == 2 ? (f).z : (f).w)

// async global->LDS, 16B per lane (HW: wave-uniform base + lane*16)
__device__ __forceinline__ void gl_lds16(const void* g, void* l) {
    __builtin_amdgcn_global_load_lds(
        (const __attribute__((address_space(1))) void*)g,
        (__attribute__((address_space(3))) void*)l, 16, 0, 0);
}

struct MoeArgs {
    const float *x, *Wg, *bg, *W1, *b1, *W2, *b2, *W3, *b3;
    float* out;
    __bf16 *xb, *h1, *h2;
    float* y;
    __bf16 *W1b, *W2b, *W3b;
    float* gates_tk;
    int *idx_tk, *t2r, *token_ids;
    double *prob_part, *gsum_part;
    int *cnt_part, *poffset, *totalp;
    int *bar;         // grid barrier counter (monotonic)
};

// software grid barrier: all NBLK blocks co-resident by construction.
// release fence before arrive, acquire fence after pass (cross-XCD L2 coherence).
__device__ __forceinline__ void grid_barrier(int* bar, int phase)
{
    __syncthreads();
    __threadfence();
    if (threadIdx.x == 0) {
        __hip_atomic_fetch_add(bar, 1, __ATOMIC_RELEASE, __HIP_MEMORY_SCOPE_AGENT);
        const int target = phase * NBLK;
        int spins = 0;
        while (__hip_atomic_load(bar, __ATOMIC_ACQUIRE, __HIP_MEMORY_SCOPE_AGENT) < target) {
            __builtin_amdgcn_s_sleep(2);
            if (++spins > (1 << 20)) break;   // failsafe: wrong-answer instead of hang
        }
    }
    __syncthreads();
    __threadfence();
}

// one LDS allocation, re-purposed per phase
union SharedU {
    struct {                       // gating
        float WgS[8][1032];
        float bgS[NE];
        double tok_p[32][NE];
        double tok_g[32][2];
        int    tok_i[32][2];
    } g;
    struct {                       // routing
        int cntE[NE], baseE[NE], po[NE + 1];
        int4 sb[256];
    } r;
    struct {                       // gemm
        __bf16 As[128 * 64];
        __bf16 Bs[128 * 64];
    } m;
    struct {                       // finalize
        double ps[NE], gs[NE];
    } f;
};

// ---------------- phase 0a: gating (blocks 0..127), round-3-verified ----------------
__device__ void gating_body(const int b, const int tid, const MoeArgs& a, SharedU& sh)
{
    for (int i = tid; i < D_IN * NE; i += 256)
        sh.g.WgS[i >> 10][i & 1023] = a.Wg[i];
    if (tid < NE) sh.g.bgS[tid] = a.bg[tid];

    {
        const size_t base = (size_t)b * 32 * D_IN;
        for (int i = tid * 4; i < 32 * D_IN; i += 256 * 4) {
            float4 v = *(const float4*)(a.x + base + i);
            bf16x4 bv = {(__bf16)v.x, (__bf16)v.y, (__bf16)v.z, (__bf16)v.w};
            *(bf16x4*)(a.xb + base + i) = bv;
        }
    }
    __syncthreads();

    const int tokL = tid >> 3;
    const int part = tid & 7;
    const int t = b * 32 + tokL;
    const float* xr = a.x + (size_t)t * D_IN + part * 128;

    double s[NE] = {0, 0, 0, 0, 0, 0, 0, 0};
    for (int j = 0; j < 128; j += 4) {
        float4 xv = *(const float4*)(xr + j);
        const float* w = &sh.g.WgS[part][j * 8];
        #pragma unroll
        for (int jj = 0; jj < 4; ++jj) {
            double xd = (double)(ELT(xv, jj));
            #pragma unroll
            for (int e = 0; e < NE; ++e)
                s[e] += xd * (double)w[jj * 8 + e];
        }
    }
    #pragma unroll
    for (int off = 4; off; off >>= 1)
        #pragma unroll
        for (int e = 0; e < NE; ++e)
            s[e] += __shfl_xor(s[e], off);

    if (part == 0) {
        double rg[NE];
        #pragma unroll
        for (int e = 0; e < NE; ++e) rg[e] = s[e] + (double)sh.g.bgS[e];
        int i0 = 0;
        #pragma unroll
        for (int e = 1; e < NE; ++e) if (rg[e] > rg[i0]) i0 = e;
        int i1 = -1;
        #pragma unroll
        for (int e = 0; e < NE; ++e) {
            if (e == i0) continue;
            if (i1 < 0 || rg[e] > rg[i1]) i1 = e;
        }
        double e1 = exp(rg[i1] - rg[i0]);
        double den = 1.0 + e1;
        a.gates_tk[t * 2] = (float)(1.0 / den); a.gates_tk[t * 2 + 1] = (float)(e1 / den);
        a.idx_tk[t * 2] = i0;   a.idx_tk[t * 2 + 1] = i1;
        sh.g.tok_g[tokL][0] = 1.0 / den; sh.g.tok_g[tokL][1] = e1 / den;
        sh.g.tok_i[tokL][0] = i0;        sh.g.tok_i[tokL][1] = i1;
        double mx = rg[0];
        #pragma unroll
        for (int e = 1; e < NE; ++e) mx = fmax(mx, rg[e]);
        double pe[NE], sum = 0.0;
        #pragma unroll
        for (int e = 0; e < NE; ++e) { pe[e] = exp(rg[e] - mx); sum += pe[e]; }
        #pragma unroll
        for (int e = 0; e < NE; ++e) sh.g.tok_p[tokL][e] = pe[e] / sum;
    }
    __syncthreads();
    if (tid < NE) {
        double p = 0.0, g = 0.0; int c = 0;
        for (int i = 0; i < 32; ++i) {
            p += sh.g.tok_p[i][tid];
            if (sh.g.tok_i[i][0] == tid) { g += sh.g.tok_g[i][0]; ++c; }
            if (sh.g.tok_i[i][1] == tid) { g += sh.g.tok_g[i][1]; ++c; }
        }
        a.prob_part[b * NE + tid] = p;
        a.gsum_part[b * NE + tid] = g;
        a.cnt_part[b * NE + tid] = c;
    }
}

// ---------------- phase 0b: weight fp32->bf16 convert (blocks 128..511) ----------------
__device__ __forceinline__ void cvt_range(const float* __restrict__ src, __bf16* __restrict__ dst,
                                          size_t n8, size_t start, size_t stride)
{
    for (size_t i = start; i < n8; i += stride) {
        float4 va = ((const float4*)src)[2 * i];
        float4 vb = ((const float4*)src)[2 * i + 1];
        bf16x8 v = {(__bf16)va.x, (__bf16)va.y, (__bf16)va.z, (__bf16)va.w,
                    (__bf16)vb.x, (__bf16)vb.y, (__bf16)vb.z, (__bf16)vb.w};
        *(bf16x8*)(dst + i * 8) = v;
    }
}

__device__ void cvt_body(const int cb, const int tid, const MoeArgs& a)
{
    const size_t start = (size_t)cb * 256 + tid;
    const size_t stride = (size_t)(NBLK - GBLK) * 256;
    cvt_range(a.W1, a.W1b, (size_t)NE * D_IN * H_DIM / 8, start, stride);
    cvt_range(a.W2, a.W2b, (size_t)NE * H_DIM * H_DIM / 8, start, stride);
    cvt_range(a.W3, a.W3b, (size_t)NE * H_DIM * O_DIM / 8, start, stride);
}

// ---------------- phase 1: scan-based routing (blocks 0..15), round-3-verified ----------------
__device__ void route_body(const int b, const int tid, const MoeArgs& a, SharedU& sh)
{
    int* cntE = sh.r.cntE; int* baseE = sh.r.baseE; int* po = sh.r.po; int4* sb = sh.r.sb;

    if (tid < NE) {
        int tot = 0, pre = 0;
        for (int g = 0; g < 128; ++g) {
            int v = a.cnt_part[g * NE + tid];
            tot += v;
            if (g < b * 8) pre += v;
        }
        cntE[tid] = tot;
        baseE[tid] = pre;
    }
    __syncthreads();
    if (tid == 0) {
        po[0] = 0;
        for (int e = 0; e < NE; ++e) po[e + 1] = po[e] + ((cntE[e] + 127) & ~127);
        if (b == 0) {
            for (int e = 0; e <= NE; ++e) a.poffset[e] = po[e];
            a.totalp[0] = po[NE];
        }
    }
    __syncthreads();

    const int t = b * 256 + tid;
    const int e0 = a.idx_tk[t * 2], e1 = a.idx_tk[t * 2 + 1];
    int4 p = {0, 0, 0, 0};
    ((int*)&p)[e0 >> 1] += 1 << ((e0 & 1) * 16);
    ((int*)&p)[e1 >> 1] += 1 << ((e1 & 1) * 16);
    sb[tid] = p;
    __syncthreads();
    for (int off = 1; off < 256; off <<= 1) {
        int4 v = sb[tid];
        int4 u = {0, 0, 0, 0};
        if (tid >= off) u = sb[tid - off];
        __syncthreads();
        v.x += u.x; v.y += u.y; v.z += u.z; v.w += u.w;
        sb[tid] = v;
        __syncthreads();
    }
    int4 inc = sb[tid];
    {
        int pos0 = ((((const int*)&inc)[e0 >> 1] >> ((e0 & 1) * 16)) & 0xffff) - 1;
        int r0 = po[e0] + baseE[e0] + pos0;
        a.token_ids[r0] = t; a.t2r[t * 2] = r0;
        int pos1 = ((((const int*)&inc)[e1 >> 1] >> ((e1 & 1) * 16)) & 0xffff) - 1;
        int r1 = po[e1] + baseE[e1] + pos1;
        a.token_ids[r1] = t; a.t2r[t * 2 + 1] = r1;
    }
    for (int e = 0; e < NE; ++e) {
        int c = cntE[e], base = po[e], pc = po[e + 1] - po[e];
        for (int i = c + b * 256 + tid; i < pc; i += 16 * 256) a.token_ids[base + i] = 0;
    }
}

// ---------------- GEMM tile: 128x128, BK=64, bf16 B reg-staged w/ verified swizzle ----------------
template<bool GATHER, bool RELU, bool OUTBF16>
__device__ __forceinline__ void gemm_tile(
    SharedU& sh, const int tid, const int n0, const int row0,
    const __bf16* __restrict__ A, int lda,
    const __bf16* __restrict__ Bw, int Kdim, int N,
    const float* __restrict__ bias,
    void* __restrict__ Out, int ldo,
    const int* __restrict__ token_ids,
    const int* __restrict__ poffset)
{
    __bf16* As = sh.m.As;
    __bf16* Bs = sh.m.Bs;
    int e = 0;
    while (e < NE - 1 && row0 >= poffset[e + 1]) ++e;
    const __bf16* Be = Bw + (size_t)e * Kdim * N;
    const float* biase = bias + (size_t)e * N;

    const int srow = tid >> 3;
    const int jperm = (tid & 7) ^ (srow & 7);
    const int scol = jperm * 8;
    int arow_g[4];
    #pragma unroll
    for (int c = 0; c < 4; ++c) {
        int r = row0 + c * 32 + srow;
        arow_g[c] = GATHER ? token_ids[r] : r;
    }

    const int rg = tid >> 5;
    const int cB = tid & 31;
    const __bf16* bsrc0 = Be + (size_t)rg * 8 * N + n0 + cB * 4;

    const int lane = tid & 63;
    const int quad = lane >> 4;
    const int m16  = lane & 15;
    const int wave = tid >> 6;
    const int wm = wave >> 1, wn = wave & 1;

    f32x4 acc[4][4];
    #pragma unroll
    for (int i = 0; i < 4; ++i)
        #pragma unroll
        for (int j = 0; j < 4; ++j)
            acc[i][j] = (f32x4){0.f, 0.f, 0.f, 0.f};

    const int niter = Kdim >> 6;

    bf16x4 r[8];
    #pragma unroll
    for (int i = 0; i < 8; ++i)
        r[i] = *(const bf16x4*)(bsrc0 + (size_t)i * N);

    for (int kt = 0; kt < niter; ++kt) {
        const int kofs = kt * 64 + scol;
        #pragma unroll
        for (int c = 0; c < 4; ++c)
            gl_lds16(A + (size_t)arow_g[c] * lda + kofs, (char*)As + c * 4096 + tid * 16);
        #pragma unroll
        for (int j = 0; j < 4; ++j) {
            const int n = cB * 4 + j;
            const int key = (n & 7) ^ ((n >> 4) & 3);
            bf16x8 v;
            #pragma unroll
            for (int i = 0; i < 8; ++i) v[i] = r[i][j];
            *(bf16x8*)&Bs[n * 64 + ((rg ^ key) << 3)] = v;
        }
        __syncthreads();
        if (kt + 1 < niter) {
            const __bf16* bsrc = bsrc0 + (size_t)(kt + 1) * 64 * N;
            #pragma unroll
            for (int i = 0; i < 8; ++i)
                r[i] = *(const bf16x4*)(bsrc + (size_t)i * N);
        }
        #pragma unroll
        for (int ks = 0; ks < 2; ++ks) {
            const int c0 = (ks << 2) | quad;
            const int pA = c0 ^ (m16 & 7);
            bf16x8 af[4], bfr[4];
            #pragma unroll
            for (int i = 0; i < 4; ++i)
                af[i] = *(const bf16x8*)&As[(wm * 64 + i * 16 + m16) * 64 + pA * 8];
            #pragma unroll
            for (int j = 0; j < 4; ++j) {
                const int pB = pA ^ j;
                bfr[j] = *(const bf16x8*)&Bs[(wn * 64 + j * 16 + m16) * 64 + pB * 8];
            }
            #pragma unroll
            for (int i = 0; i < 4; ++i)
                #pragma unroll
                for (int j = 0; j < 4; ++j)
                    acc[i][j] = __builtin_amdgcn_mfma_f32_16x16x32_bf16(af[i], bfr[j], acc[i][j], 0, 0, 0);
        }
        __syncthreads();
    }
    #pragma unroll
    for (int i = 0; i < 4; ++i)
        #pragma unroll
        for (int j = 0; j < 4; ++j)
            #pragma unroll
            for (int rr = 0; rr < 4; ++rr) {
                int grow = row0 + wm * 64 + i * 16 + quad * 4 + rr;
                int gcol = n0 + wn * 64 + j * 16 + m16;
                float v = acc[i][j][rr] + biase[gcol];
                if (RELU) v = v > 0.f ? v : 0.f;
                if (OUTBF16) ((__bf16*)Out)[(size_t)grow * ldo + gcol] = (__bf16)v;
                else         ((float*)Out)[(size_t)grow * ldo + gcol] = v;
            }
}

// persistent tile loop over one layer; n-tile fastest (A slab L2-sharing)
template<bool GATHER, bool RELU, bool OUTBF16>
__device__ void gemm_phase(
    SharedU& sh, const int bid, const int tid, const MoeArgs& a,
    const __bf16* A, int lda, const __bf16* Bw, int Kdim, int N,
    const float* bias, void* Out, int ldo)
{
    const int rtiles = (a.totalp[0] + 127) >> 7;
    const int nx = N >> 7;
    const int ntiles = nx * rtiles;
    for (int tile = bid; tile < ntiles; tile += NBLK) {
        const int n0 = (tile % nx) * 128;
        const int row0 = (tile / nx) * 128;
        gemm_tile<GATHER, RELU, OUTBF16>(sh, tid, n0, row0, A, lda, Bw, Kdim, N,
                                         bias, Out, ldo, a.token_ids, a.poffset);
    }
}

// ---------------- phase 5: combine (+ finalize in block 0) ----------------
__device__ void combine_body(const int bid, const int tid, const MoeArgs& a, SharedU& sh)
{
    if (bid == 0) {
        if (tid < NE) {
            double p = 0.0, g = 0.0;
            for (int bb = 0; bb < 128; ++bb) {
                p += a.prob_part[bb * NE + tid];
                g += a.gsum_part[bb * NE + tid];
            }
            sh.f.ps[tid] = p / (double)T_TOK;
            sh.f.gs[tid] = g / (double)T_TOK;
            a.out[(size_t)T_TOK * O_DIM + 1 + tid] = (float)(g / (double)T_TOK);
        }
        __syncthreads();
        if (tid == 0) {
            double lb = 0.0, ent = 0.0;
            for (int e = 0; e < NE; ++e) {
                lb += sh.f.ps[e] * sh.f.gs[e];
                ent -= sh.f.ps[e] * log(sh.f.ps[e] + 1e-8);
            }
            a.out[(size_t)T_TOK * O_DIM] = (float)(0.01 * 8.0 * lb);
            a.out[(size_t)T_TOK * O_DIM + 9] = (float)ent;
        }
    }
    const int o = tid * 4;
    for (int t = bid; t < T_TOK; t += NBLK) {
        const int r0 = a.t2r[t * 2], r1 = a.t2r[t * 2 + 1];
        const float g0 = a.gates_tk[t * 2], g1 = a.gates_tk[t * 2 + 1];
        float4 va = *(const float4*)&a.y[(size_t)r0 * O_DIM + o];
        float4 vb = *(const float4*)&a.y[(size_t)r1 * O_DIM + o];
        float4 c;
        c.x = g0 * va.x + g1 * vb.x;
        c.y = g0 * va.y + g1 * vb.y;
        c.z = g0 * va.z + g1 * vb.z;
        c.w = g0 * va.w + g1 * vb.w;
        *(float4*)&a.out[(size_t)t * O_DIM + o] = c;
    }
}

// ---------------- the single mega kernel (software grid barrier) ----------------
__global__ __launch_bounds__(256, 2) void moe_mega(MoeArgs a)
{
    __shared__ SharedU sh;
    const int bid = blockIdx.x;
    const int tid = threadIdx.x;

    // phase 0: gating | weight convert
    if (bid < GBLK) gating_body(bid, tid, a, sh);
    else            cvt_body(bid - GBLK, tid, a);
    grid_barrier(a.bar, 1);

    // phase 1: routing
    if (bid < 16) route_body(bid, tid, a, sh);
    grid_barrier(a.bar, 2);

    // phases 2-4: expert GEMMs
    gemm_phase<true,  true,  true >(sh, bid, tid, a, a.xb, D_IN, a.W1b, D_IN, H_DIM,
                                    a.b1, (void*)a.h1, H_DIM);
    grid_barrier(a.bar, 3);
    gemm_phase<false, true,  true >(sh, bid, tid, a, a.h1, H_DIM, a.W2b, H_DIM, H_DIM,
                                    a.b2, (void*)a.h2, H_DIM);
    grid_barrier(a.bar, 4);
    gemm_phase<false, false, false>(sh, bid, tid, a, a.h2, H_DIM, a.W3b, H_DIM, O_DIM,
                                    a.b3, (void*)a.y, O_DIM);
    grid_barrier(a.bar, 5);

    // phase 5: combine + finalize
    combine_body(bid, tid, a, sh);
}

// ---------------- launch: memset(barrier) + ONE kernel ----------------
extern "C" void kernel_launch(void* const* d_in, const int* in_sizes, int n_in,
                              void* d_out, int out_size, void* d_ws, size_t ws_size,
                              hipStream_t stream)
{
    char* ws = (char*)d_ws;
    size_t off = 0;
    __bf16* xb  = (__bf16*)(ws + off); off += (size_t)T_TOK * D_IN * 2;
    __bf16* h1  = (__bf16*)(ws + off);
    float*  y   = (float*) (ws + off); off += (size_t)ROWCAP * H_DIM * 2;  // h1 (bf16) / y (f32) alias
    __bf16* h2  = (__bf16*)(ws + off); off += (size_t)ROWCAP * H_DIM * 2;
    __bf16* W1b = (__bf16*)(ws + off); off += (size_t)NE * D_IN * H_DIM * 2;
    __bf16* W2b = (__bf16*)(ws + off); off += (size_t)NE * H_DIM * H_DIM * 2;
    __bf16* W3b = (__bf16*)(ws + off); off += (size_t)NE * H_DIM * O_DIM * 2;
    float* gates_tk = (float*)(ws + off); off += T_TOK * 2 * 4;
    int* idx_tk     = (int*)(ws + off);   off += T_TOK * 2 * 4;
    int* t2r        = (int*)(ws + off);   off += T_TOK * 2 * 4;
    int* token_ids  = (int*)(ws + off);   off += ROWCAP * 4;
    double* prob_part = (double*)(ws + off); off += 128 * NE * 8;
    double* gsum_part = (double*)(ws + off); off += 128 * NE * 8;
    int* cnt_part   = (int*)(ws + off);   off += 128 * NE * 4;
    int* poffset    = (int*)(ws + off);   off += (NE + 1) * 4;
    int* totalp     = (int*)(ws + off);   off += 16;
    int* bar        = (int*)(ws + off);   off += 64;

    hipMemsetAsync(bar, 0, 64, stream);

    MoeArgs a;
    a.x  = (const float*)d_in[0];
    a.Wg = (const float*)d_in[1];
    a.bg = (const float*)d_in[2];
    a.W1 = (const float*)d_in[3];
    a.b1 = (const float*)d_in[4];
    a.W2 = (const float*)d_in[5];
    a.b2 = (const float*)d_in[6];
    a.W3 = (const float*)d_in[7];
    a.b3 = (const float*)d_in[8];
    a.out = (float*)d_out;
    a.xb = xb; a.h1 = h1; a.h2 = h2; a.y = y;
    a.W1b = W1b; a.W2b = W2b; a.W3b = W3b;
    a.gates_tk = gates_tk; a.idx_tk = idx_tk; a.t2r = t2r; a.token_ids = token_ids;
    a.prob_part = prob_part; a.gsum_part = gsum_part; a.cnt_part = cnt_part;
    a.poffset = poffset; a.totalp = totalp;
    a.bar = bar;

    moe_mega<<<dim3(NBLK), dim3(256), 0, stream>>>(a);
}

// Round 6
// 934.982 us; speedup vs baseline: 1.8787x; 1.8787x over previous
//
#include <hip/hip_runtime.h>
#include <hip/hip_bf16.h>
#include <math.h>

// Problem constants
#define T_TOK 4096   // B*S tokens
#define D_IN  1024
#define H_DIM 2048
#define O_DIM 1024
#define NE    8
#define ROWCAP 9216  // 8192 routed rows + per-expert pad to 128
#define NBLK  512    // grid: 2 blocks/CU guaranteed by launch_bounds(256,2) + 40KB LDS
#define GBLK  128    // blocks [0,GBLK) gate; [GBLK,NBLK) convert weights in phase 0

typedef __bf16 bf16x8 __attribute__((ext_vector_type(8)));
typedef __bf16 bf16x4 __attribute__((ext_vector_type(4)));
typedef float  f32x4  __attribute__((ext_vector_type(4)));

#define ELT(f, j) ((j) == 0 ? (f).x : (j) == 1 ? (f).y : (j) == 2 ? (f).z : (f).w)

// async global->LDS, 16B per lane (HW: wave-uniform base + lane*16)
__device__ __forceinline__ void gl_lds16(const void* g, void* l) {
    __builtin_amdgcn_global_load_lds(
        (const __attribute__((address_space(1))) void*)g,
        (__attribute__((address_space(3))) void*)l, 16, 0, 0);
}

struct MoeArgs {
    const float *x, *Wg, *bg, *W1, *b1, *W2, *b2, *W3, *b3;
    float* out;
    __bf16 *xb, *h1, *h2;
    float* y;
    __bf16 *W1b, *W2b, *W3b;
    float* gates_tk;
    int *idx_tk, *t2r, *token_ids;
    double *prob_part, *gsum_part;
    int *cnt_part, *poffset, *totalp;
    int *bar;         // grid barrier counter (monotonic)
};

// Software grid barrier, fence-storm-free (round-5 lesson):
//  - entry __syncthreads drains vmcnt(0) -> all block writes are in this XCD's L2
//  - ONE __threadfence by thread 0 (wbl2) pushes them to the coherence point
//  - spin uses RELAXED loads (NO buffer_inv per poll!) + s_sleep(32)
//  - ONE __threadfence after the spin (buffer_inv) = acquire before releasing the block
// Round-5's ACQUIRE-poll invalidated every XCD L2 ~18M/s -> 3x collapse.
__device__ __forceinline__ void grid_barrier(int* bar, int phase)
{
    __syncthreads();
    if (threadIdx.x == 0) {
        __threadfence();   // release: writeback L2 -> LLC (once per block)
        __hip_atomic_fetch_add(bar, 1, __ATOMIC_RELAXED, __HIP_MEMORY_SCOPE_AGENT);
        const int target = phase * NBLK;
        int spins = 0;
        while (__hip_atomic_load(bar, __ATOMIC_RELAXED, __HIP_MEMORY_SCOPE_AGENT) < target) {
            __builtin_amdgcn_s_sleep(32);
            if (++spins > (1 << 17)) break;   // failsafe: wrong-answer instead of hang
        }
        __threadfence();   // acquire: invalidate stale L1/L2 before next phase reads
    }
    __syncthreads();
}

// one LDS allocation, re-purposed per phase
union SharedU {
    struct {                       // gating
        float WgS[8][1032];
        float bgS[NE];
        double tok_p[32][NE];
        double tok_g[32][2];
        int    tok_i[32][2];
    } g;
    struct {                       // routing
        int cntE[NE], baseE[NE], po[NE + 1];
        int4 sb[256];
    } r;
    struct {                       // gemm
        __bf16 As[128 * 64];
        __bf16 Bs[128 * 64];
    } m;
    struct {                       // finalize
        double ps[NE], gs[NE];
    } f;
};

// ---------------- phase 0a: gating (blocks 0..127), round-3-verified ----------------
__device__ void gating_body(const int b, const int tid, const MoeArgs& a, SharedU& sh)
{
    for (int i = tid; i < D_IN * NE; i += 256)
        sh.g.WgS[i >> 10][i & 1023] = a.Wg[i];
    if (tid < NE) sh.g.bgS[tid] = a.bg[tid];

    {
        const size_t base = (size_t)b * 32 * D_IN;
        for (int i = tid * 4; i < 32 * D_IN; i += 256 * 4) {
            float4 v = *(const float4*)(a.x + base + i);
            bf16x4 bv = {(__bf16)v.x, (__bf16)v.y, (__bf16)v.z, (__bf16)v.w};
            *(bf16x4*)(a.xb + base + i) = bv;
        }
    }
    __syncthreads();

    const int tokL = tid >> 3;
    const int part = tid & 7;
    const int t = b * 32 + tokL;
    const float* xr = a.x + (size_t)t * D_IN + part * 128;

    double s[NE] = {0, 0, 0, 0, 0, 0, 0, 0};
    for (int j = 0; j < 128; j += 4) {
        float4 xv = *(const float4*)(xr + j);
        const float* w = &sh.g.WgS[part][j * 8];
        #pragma unroll
        for (int jj = 0; jj < 4; ++jj) {
            double xd = (double)(ELT(xv, jj));
            #pragma unroll
            for (int e = 0; e < NE; ++e)
                s[e] += xd * (double)w[jj * 8 + e];
        }
    }
    #pragma unroll
    for (int off = 4; off; off >>= 1)
        #pragma unroll
        for (int e = 0; e < NE; ++e)
            s[e] += __shfl_xor(s[e], off);

    if (part == 0) {
        double rg[NE];
        #pragma unroll
        for (int e = 0; e < NE; ++e) rg[e] = s[e] + (double)sh.g.bgS[e];
        int i0 = 0;
        #pragma unroll
        for (int e = 1; e < NE; ++e) if (rg[e] > rg[i0]) i0 = e;
        int i1 = -1;
        #pragma unroll
        for (int e = 0; e < NE; ++e) {
            if (e == i0) continue;
            if (i1 < 0 || rg[e] > rg[i1]) i1 = e;
        }
        double e1 = exp(rg[i1] - rg[i0]);
        double den = 1.0 + e1;
        a.gates_tk[t * 2] = (float)(1.0 / den); a.gates_tk[t * 2 + 1] = (float)(e1 / den);
        a.idx_tk[t * 2] = i0;   a.idx_tk[t * 2 + 1] = i1;
        sh.g.tok_g[tokL][0] = 1.0 / den; sh.g.tok_g[tokL][1] = e1 / den;
        sh.g.tok_i[tokL][0] = i0;        sh.g.tok_i[tokL][1] = i1;
        double mx = rg[0];
        #pragma unroll
        for (int e = 1; e < NE; ++e) mx = fmax(mx, rg[e]);
        double pe[NE], sum = 0.0;
        #pragma unroll
        for (int e = 0; e < NE; ++e) { pe[e] = exp(rg[e] - mx); sum += pe[e]; }
        #pragma unroll
        for (int e = 0; e < NE; ++e) sh.g.tok_p[tokL][e] = pe[e] / sum;
    }
    __syncthreads();
    if (tid < NE) {
        double p = 0.0, g = 0.0; int c = 0;
        for (int i = 0; i < 32; ++i) {
            p += sh.g.tok_p[i][tid];
            if (sh.g.tok_i[i][0] == tid) { g += sh.g.tok_g[i][0]; ++c; }
            if (sh.g.tok_i[i][1] == tid) { g += sh.g.tok_g[i][1]; ++c; }
        }
        a.prob_part[b * NE + tid] = p;
        a.gsum_part[b * NE + tid] = g;
        a.cnt_part[b * NE + tid] = c;
    }
}

// ---------------- phase 0b: weight fp32->bf16 convert (blocks 128..511) ----------------
__device__ __forceinline__ void cvt_range(const float* __restrict__ src, __bf16* __restrict__ dst,
                                          size_t n8, size_t start, size_t stride)
{
    for (size_t i = start; i < n8; i += stride) {
        float4 va = ((const float4*)src)[2 * i];
        float4 vb = ((const float4*)src)[2 * i + 1];
        bf16x8 v = {(__bf16)va.x, (__bf16)va.y, (__bf16)va.z, (__bf16)va.w,
                    (__bf16)vb.x, (__bf16)vb.y, (__bf16)vb.z, (__bf16)vb.w};
        *(bf16x8*)(dst + i * 8) = v;
    }
}

__device__ void cvt_body(const int cb, const int tid, const MoeArgs& a)
{
    const size_t start = (size_t)cb * 256 + tid;
    const size_t stride = (size_t)(NBLK - GBLK) * 256;
    cvt_range(a.W1, a.W1b, (size_t)NE * D_IN * H_DIM / 8, start, stride);
    cvt_range(a.W2, a.W2b, (size_t)NE * H_DIM * H_DIM / 8, start, stride);
    cvt_range(a.W3, a.W3b, (size_t)NE * H_DIM * O_DIM / 8, start, stride);
}

// ---------------- phase 1: scan-based routing (blocks 0..15), round-3-verified ----------------
__device__ void route_body(const int b, const int tid, const MoeArgs& a, SharedU& sh)
{
    int* cntE = sh.r.cntE; int* baseE = sh.r.baseE; int* po = sh.r.po; int4* sb = sh.r.sb;

    if (tid < NE) {
        int tot = 0, pre = 0;
        for (int g = 0; g < 128; ++g) {
            int v = a.cnt_part[g * NE + tid];
            tot += v;
            if (g < b * 8) pre += v;
        }
        cntE[tid] = tot;
        baseE[tid] = pre;
    }
    __syncthreads();
    if (tid == 0) {
        po[0] = 0;
        for (int e = 0; e < NE; ++e) po[e + 1] = po[e] + ((cntE[e] + 127) & ~127);
        if (b == 0) {
            for (int e = 0; e <= NE; ++e) a.poffset[e] = po[e];
            a.totalp[0] = po[NE];
        }
    }
    __syncthreads();

    const int t = b * 256 + tid;
    const int e0 = a.idx_tk[t * 2], e1 = a.idx_tk[t * 2 + 1];
    int4 p = {0, 0, 0, 0};
    ((int*)&p)[e0 >> 1] += 1 << ((e0 & 1) * 16);
    ((int*)&p)[e1 >> 1] += 1 << ((e1 & 1) * 16);
    sb[tid] = p;
    __syncthreads();
    for (int off = 1; off < 256; off <<= 1) {
        int4 v = sb[tid];
        int4 u = {0, 0, 0, 0};
        if (tid >= off) u = sb[tid - off];
        __syncthreads();
        v.x += u.x; v.y += u.y; v.z += u.z; v.w += u.w;
        sb[tid] = v;
        __syncthreads();
    }
    int4 inc = sb[tid];
    {
        int pos0 = ((((const int*)&inc)[e0 >> 1] >> ((e0 & 1) * 16)) & 0xffff) - 1;
        int r0 = po[e0] + baseE[e0] + pos0;
        a.token_ids[r0] = t; a.t2r[t * 2] = r0;
        int pos1 = ((((const int*)&inc)[e1 >> 1] >> ((e1 & 1) * 16)) & 0xffff) - 1;
        int r1 = po[e1] + baseE[e1] + pos1;
        a.token_ids[r1] = t; a.t2r[t * 2 + 1] = r1;
    }
    for (int e = 0; e < NE; ++e) {
        int c = cntE[e], base = po[e], pc = po[e + 1] - po[e];
        for (int i = c + b * 256 + tid; i < pc; i += 16 * 256) a.token_ids[base + i] = 0;
    }
}

// ---------------- GEMM tile: 128x128, BK=64, bf16 B reg-staged w/ verified swizzle ----------------
template<bool GATHER, bool RELU, bool OUTBF16>
__device__ __forceinline__ void gemm_tile(
    SharedU& sh, const int tid, const int n0, const int row0,
    const __bf16* __restrict__ A, int lda,
    const __bf16* __restrict__ Bw, int Kdim, int N,
    const float* __restrict__ bias,
    void* __restrict__ Out, int ldo,
    const int* __restrict__ token_ids,
    const int* __restrict__ poffset)
{
    __bf16* As = sh.m.As;
    __bf16* Bs = sh.m.Bs;
    int e = 0;
    while (e < NE - 1 && row0 >= poffset[e + 1]) ++e;
    const __bf16* Be = Bw + (size_t)e * Kdim * N;
    const float* biase = bias + (size_t)e * N;

    const int srow = tid >> 3;
    const int jperm = (tid & 7) ^ (srow & 7);
    const int scol = jperm * 8;
    int arow_g[4];
    #pragma unroll
    for (int c = 0; c < 4; ++c) {
        int r = row0 + c * 32 + srow;
        arow_g[c] = GATHER ? token_ids[r] : r;
    }

    const int rg = tid >> 5;
    const int cB = tid & 31;
    const __bf16* bsrc0 = Be + (size_t)rg * 8 * N + n0 + cB * 4;

    const int lane = tid & 63;
    const int quad = lane >> 4;
    const int m16  = lane & 15;
    const int wave = tid >> 6;
    const int wm = wave >> 1, wn = wave & 1;

    f32x4 acc[4][4];
    #pragma unroll
    for (int i = 0; i < 4; ++i)
        #pragma unroll
        for (int j = 0; j < 4; ++j)
            acc[i][j] = (f32x4){0.f, 0.f, 0.f, 0.f};

    const int niter = Kdim >> 6;

    bf16x4 r[8];
    #pragma unroll
    for (int i = 0; i < 8; ++i)
        r[i] = *(const bf16x4*)(bsrc0 + (size_t)i * N);

    for (int kt = 0; kt < niter; ++kt) {
        const int kofs = kt * 64 + scol;
        #pragma unroll
        for (int c = 0; c < 4; ++c)
            gl_lds16(A + (size_t)arow_g[c] * lda + kofs, (char*)As + c * 4096 + tid * 16);
        #pragma unroll
        for (int j = 0; j < 4; ++j) {
            const int n = cB * 4 + j;
            const int key = (n & 7) ^ ((n >> 4) & 3);
            bf16x8 v;
            #pragma unroll
            for (int i = 0; i < 8; ++i) v[i] = r[i][j];
            *(bf16x8*)&Bs[n * 64 + ((rg ^ key) << 3)] = v;
        }
        __syncthreads();
        if (kt + 1 < niter) {
            const __bf16* bsrc = bsrc0 + (size_t)(kt + 1) * 64 * N;
            #pragma unroll
            for (int i = 0; i < 8; ++i)
                r[i] = *(const bf16x4*)(bsrc + (size_t)i * N);
        }
        #pragma unroll
        for (int ks = 0; ks < 2; ++ks) {
            const int c0 = (ks << 2) | quad;
            const int pA = c0 ^ (m16 & 7);
            bf16x8 af[4], bfr[4];
            #pragma unroll
            for (int i = 0; i < 4; ++i)
                af[i] = *(const bf16x8*)&As[(wm * 64 + i * 16 + m16) * 64 + pA * 8];
            #pragma unroll
            for (int j = 0; j < 4; ++j) {
                const int pB = pA ^ j;
                bfr[j] = *(const bf16x8*)&Bs[(wn * 64 + j * 16 + m16) * 64 + pB * 8];
            }
            #pragma unroll
            for (int i = 0; i < 4; ++i)
                #pragma unroll
                for (int j = 0; j < 4; ++j)
                    acc[i][j] = __builtin_amdgcn_mfma_f32_16x16x32_bf16(af[i], bfr[j], acc[i][j], 0, 0, 0);
        }
        __syncthreads();
    }
    #pragma unroll
    for (int i = 0; i < 4; ++i)
        #pragma unroll
        for (int j = 0; j < 4; ++j)
            #pragma unroll
            for (int rr = 0; rr < 4; ++rr) {
                int grow = row0 + wm * 64 + i * 16 + quad * 4 + rr;
                int gcol = n0 + wn * 64 + j * 16 + m16;
                float v = acc[i][j][rr] + biase[gcol];
                if (RELU) v = v > 0.f ? v : 0.f;
                if (OUTBF16) ((__bf16*)Out)[(size_t)grow * ldo + gcol] = (__bf16)v;
                else         ((float*)Out)[(size_t)grow * ldo + gcol] = v;
            }
}

// persistent tile loop over one layer; n-tile fastest (A slab L2-sharing)
template<bool GATHER, bool RELU, bool OUTBF16>
__device__ void gemm_phase(
    SharedU& sh, const int bid, const int tid, const MoeArgs& a,
    const __bf16* A, int lda, const __bf16* Bw, int Kdim, int N,
    const float* bias, void* Out, int ldo)
{
    const int rtiles = (a.totalp[0] + 127) >> 7;
    const int nx = N >> 7;
    const int ntiles = nx * rtiles;
    for (int tile = bid; tile < ntiles; tile += NBLK) {
        const int n0 = (tile % nx) * 128;
        const int row0 = (tile / nx) * 128;
        gemm_tile<GATHER, RELU, OUTBF16>(sh, tid, n0, row0, A, lda, Bw, Kdim, N,
                                         bias, Out, ldo, a.token_ids, a.poffset);
    }
}

// ---------------- phase 5: combine (+ finalize in block 0) ----------------
__device__ void combine_body(const int bid, const int tid, const MoeArgs& a, SharedU& sh)
{
    if (bid == 0) {
        if (tid < NE) {
            double p = 0.0, g = 0.0;
            for (int bb = 0; bb < 128; ++bb) {
                p += a.prob_part[bb * NE + tid];
                g += a.gsum_part[bb * NE + tid];
            }
            sh.f.ps[tid] = p / (double)T_TOK;
            sh.f.gs[tid] = g / (double)T_TOK;
            a.out[(size_t)T_TOK * O_DIM + 1 + tid] = (float)(g / (double)T_TOK);
        }
        __syncthreads();
        if (tid == 0) {
            double lb = 0.0, ent = 0.0;
            for (int e = 0; e < NE; ++e) {
                lb += sh.f.ps[e] * sh.f.gs[e];
                ent -= sh.f.ps[e] * log(sh.f.ps[e] + 1e-8);
            }
            a.out[(size_t)T_TOK * O_DIM] = (float)(0.01 * 8.0 * lb);
            a.out[(size_t)T_TOK * O_DIM + 9] = (float)ent;
        }
    }
    const int o = tid * 4;
    for (int t = bid; t < T_TOK; t += NBLK) {
        const int r0 = a.t2r[t * 2], r1 = a.t2r[t * 2 + 1];
        const float g0 = a.gates_tk[t * 2], g1 = a.gates_tk[t * 2 + 1];
        float4 va = *(const float4*)&a.y[(size_t)r0 * O_DIM + o];
        float4 vb = *(const float4*)&a.y[(size_t)r1 * O_DIM + o];
        float4 c;
        c.x = g0 * va.x + g1 * vb.x;
        c.y = g0 * va.y + g1 * vb.y;
        c.z = g0 * va.z + g1 * vb.z;
        c.w = g0 * va.w + g1 * vb.w;
        *(float4*)&a.out[(size_t)t * O_DIM + o] = c;
    }
}

// ---------------- the single mega kernel (software grid barrier) ----------------
__global__ __launch_bounds__(256, 2) void moe_mega(MoeArgs a)
{
    __shared__ SharedU sh;
    const int bid = blockIdx.x;
    const int tid = threadIdx.x;

    // phase 0: gating | weight convert
    if (bid < GBLK) gating_body(bid, tid, a, sh);
    else            cvt_body(bid - GBLK, tid, a);
    grid_barrier(a.bar, 1);

    // phase 1: routing
    if (bid < 16) route_body(bid, tid, a, sh);
    grid_barrier(a.bar, 2);

    // phases 2-4: expert GEMMs
    gemm_phase<true,  true,  true >(sh, bid, tid, a, a.xb, D_IN, a.W1b, D_IN, H_DIM,
                                    a.b1, (void*)a.h1, H_DIM);
    grid_barrier(a.bar, 3);
    gemm_phase<false, true,  true >(sh, bid, tid, a, a.h1, H_DIM, a.W2b, H_DIM, H_DIM,
                                    a.b2, (void*)a.h2, H_DIM);
    grid_barrier(a.bar, 4);
    gemm_phase<false, false, false>(sh, bid, tid, a, a.h2, H_DIM, a.W3b, H_DIM, O_DIM,
                                    a.b3, (void*)a.y, O_DIM);
    grid_barrier(a.bar, 5);

    // phase 5: combine + finalize
    combine_body(bid, tid, a, sh);
}

// ---------------- launch: memset(barrier) + ONE kernel ----------------
extern "C" void kernel_launch(void* const* d_in, const int* in_sizes, int n_in,
                              void* d_out, int out_size, void* d_ws, size_t ws_size,
                              hipStream_t stream)
{
    char* ws = (char*)d_ws;
    size_t off = 0;
    __bf16* xb  = (__bf16*)(ws + off); off += (size_t)T_TOK * D_IN * 2;
    __bf16* h1  = (__bf16*)(ws + off);
    float*  y   = (float*) (ws + off); off += (size_t)ROWCAP * H_DIM * 2;  // h1 (bf16) / y (f32) alias
    __bf16* h2  = (__bf16*)(ws + off); off += (size_t)ROWCAP * H_DIM * 2;
    __bf16* W1b = (__bf16*)(ws + off); off += (size_t)NE * D_IN * H_DIM * 2;
    __bf16* W2b = (__bf16*)(ws + off); off += (size_t)NE * H_DIM * H_DIM * 2;
    __bf16* W3b = (__bf16*)(ws + off); off += (size_t)NE * H_DIM * O_DIM * 2;
    float* gates_tk = (float*)(ws + off); off += T_TOK * 2 * 4;
    int* idx_tk     = (int*)(ws + off);   off += T_TOK * 2 * 4;
    int* t2r        = (int*)(ws + off);   off += T_TOK * 2 * 4;
    int* token_ids  = (int*)(ws + off);   off += ROWCAP * 4;
    double* prob_part = (double*)(ws + off); off += 128 * NE * 8;
    double* gsum_part = (double*)(ws + off); off += 128 * NE * 8;
    int* cnt_part   = (int*)(ws + off);   off += 128 * NE * 4;
    int* poffset    = (int*)(ws + off);   off += (NE + 1) * 4;
    int* totalp     = (int*)(ws + off);   off += 16;
    int* bar        = (int*)(ws + off);   off += 64;

    hipMemsetAsync(bar, 0, 64, stream);

    MoeArgs a;
    a.x  = (const float*)d_in[0];
    a.Wg = (const float*)d_in[1];
    a.bg = (const float*)d_in[2];
    a.W1 = (const float*)d_in[3];
    a.b1 = (const float*)d_in[4];
    a.W2 = (const float*)d_in[5];
    a.b2 = (const float*)d_in[6];
    a.W3 = (const float*)d_in[7];
    a.b3 = (const float*)d_in[8];
    a.out = (float*)d_out;
    a.xb = xb; a.h1 = h1; a.h2 = h2; a.y = y;
    a.W1b = W1b; a.W2b = W2b; a.W3b = W3b;
    a.gates_tk = gates_tk; a.idx_tk = idx_tk; a.t2r = t2r; a.token_ids = token_ids;
    a.prob_part = prob_part; a.gsum_part = gsum_part; a.cnt_part = cnt_part;
    a.poffset = poffset; a.totalp = totalp;
    a.bar = bar;

    moe_mega<<<dim3(NBLK), dim3(256), 0, stream>>>(a);
}